// Round 16
// baseline (167.396 us; speedup 1.0000x reference)
//
#include <hip/hip_runtime.h>
#include <hip/hip_bf16.h>

typedef __hip_bfloat16 bf16;
typedef __attribute__((ext_vector_type(8))) short bf16x8;
typedef __attribute__((ext_vector_type(4))) float f32x4;
typedef __attribute__((ext_vector_type(4))) unsigned int u32x4;

#define MFMA_BF16(a, b, c) __builtin_amdgcn_mfma_f32_16x16x32_bf16((a), (b), (c), 0, 0, 0)

static constexpr int B_  = 2;
static constexpr int S_  = 2048;
static constexpr int DM_ = 1024;
static constexpr int H_  = 16;
static constexpr int D_  = 64;
static constexpr int M_  = B_ * S_;   // 4096 rows for all GEMMs

__device__ __forceinline__ void load16(const void* g, void* l) {
  __builtin_amdgcn_global_load_lds(
      (const __attribute__((address_space(1))) void*)g,
      (__attribute__((address_space(3))) void*)l, 16, 0, 0);
}

__device__ __forceinline__ unsigned int pack_bf16(float lo, float hi) {
  const unsigned int ul = __builtin_bit_cast(unsigned short, __float2bfloat16(lo));
  const unsigned int uh = __builtin_bit_cast(unsigned short, __float2bfloat16(hi));
  return (uh << 16) | ul;
}

// ---------------- fused prep: 4x weight transpose + x cvt ----------------
__global__ void prep_kernel(const float* __restrict__ w0,
                            const float* __restrict__ w1,
                            const float* __restrict__ w2,
                            const float* __restrict__ w3,
                            const float* __restrict__ x,
                            bf16* __restrict__ o0, bf16* __restrict__ o1,
                            bf16* __restrict__ o2, bf16* __restrict__ o3,
                            bf16* __restrict__ xb) {
  if (blockIdx.z == 4) {
    const int blk = blockIdx.y * 32 + blockIdx.x;   // 0..1023
#pragma unroll
    for (int rep = 0; rep < 4; ++rep) {
      const int i = blk * 1024 + rep * 256 + threadIdx.x;  // float4 index
      float4 v = ((const float4*)x)[i];
      ushort4 u;
      u.x = __builtin_bit_cast(unsigned short, __float2bfloat16(v.x));
      u.y = __builtin_bit_cast(unsigned short, __float2bfloat16(v.y));
      u.z = __builtin_bit_cast(unsigned short, __float2bfloat16(v.z));
      u.w = __builtin_bit_cast(unsigned short, __float2bfloat16(v.w));
      ((ushort4*)xb)[i] = u;
    }
    return;
  }
  __shared__ float t[32][33];
  const float* in = blockIdx.z == 0 ? w0 : blockIdx.z == 1 ? w1 : blockIdx.z == 2 ? w2 : w3;
  bf16* out = blockIdx.z == 0 ? o0 : blockIdx.z == 1 ? o1 : blockIdx.z == 2 ? o2 : o3;
  int tx = threadIdx.x & 31;
  int ty = threadIdx.x >> 5;  // 0..7
  int r0 = blockIdx.y * 32;
  int c0 = blockIdx.x * 32;
#pragma unroll
  for (int yy = 0; yy < 32; yy += 8)
    t[ty + yy][tx] = in[(size_t)(r0 + ty + yy) * DM_ + c0 + tx];
  __syncthreads();
#pragma unroll
  for (int yy = 0; yy < 32; yy += 8)
    out[(size_t)(c0 + ty + yy) * DM_ + r0 + tx] = __float2bfloat16(t[tx][ty + yy]);
}

// ---------------- QKV GEMM (2-phase, 128x128, proven) ----------------
__global__ __launch_bounds__(256) void gemm_qkv_kernel(
    const bf16* __restrict__ A, const bf16* __restrict__ Bt,
    const float* __restrict__ bias, const float* __restrict__ bias2,
    const float* __restrict__ bias3, bf16* __restrict__ out, int K) {
  __shared__ bf16 As[2][128 * 32];
  __shared__ bf16 Bs[2][128 * 32];
  const int tid = threadIdx.x;
  const int wid = tid >> 6, lane = tid & 63;
  const int g = lane >> 4, c = lane & 15;
  const int wr = wid >> 1, wc = wid & 1;
  const int bm = blockIdx.x, bn = blockIdx.y;

  f32x4 acc[4][4] = {};

  const char* Ag = (const char*)(A + (size_t)bm * 128 * K);
  const char* Bg = (const char*)(Bt + (size_t)bn * 128 * K);
  const int f0 = tid * 16, f1 = f0 + 4096;
  const int r0 = f0 >> 6, cb0 = f0 & 63;
  const int r1 = f1 >> 6;
  const size_t rowbytes = (size_t)K * 2;

  auto stage = [&](int kt, int bufi) {
    const size_t koff = (size_t)kt * 64;
    load16(Ag + (size_t)r0 * rowbytes + koff + cb0, (char*)As[bufi] + f0);
    load16(Ag + (size_t)r1 * rowbytes + koff + cb0, (char*)As[bufi] + f1);
    load16(Bg + (size_t)r0 * rowbytes + koff + cb0, (char*)Bs[bufi] + f0);
    load16(Bg + (size_t)r1 * rowbytes + koff + cb0, (char*)Bs[bufi] + f1);
  };

  const int NT = K / 32;
  stage(0, 0);
  int cur = 0;
#pragma unroll 1
  for (int kt = 0; kt < NT; ++kt) {
    if (kt + 1 < NT) {
      stage(kt + 1, cur ^ 1);
      asm volatile("s_waitcnt vmcnt(4)" ::: "memory");
    } else {
      asm volatile("s_waitcnt vmcnt(0)" ::: "memory");
    }
    __builtin_amdgcn_s_barrier();

    bf16x8 af[4], bfr[4];
#pragma unroll
    for (int mi = 0; mi < 4; ++mi)
      af[mi] = *(const bf16x8*)&As[cur][(wr * 64 + mi * 16 + c) * 32 + g * 8];
#pragma unroll
    for (int ni = 0; ni < 4; ++ni)
      bfr[ni] = *(const bf16x8*)&Bs[cur][(wc * 64 + ni * 16 + c) * 32 + g * 8];
    __builtin_amdgcn_s_setprio(1);
#pragma unroll
    for (int mi = 0; mi < 4; ++mi)
#pragma unroll
      for (int ni = 0; ni < 4; ++ni)
        acc[mi][ni] = MFMA_BF16(af[mi], bfr[ni], acc[mi][ni]);
    __builtin_amdgcn_s_setprio(0);

    if (kt + 1 < NT) __builtin_amdgcn_s_barrier();
    cur ^= 1;
  }

#pragma unroll
  for (int ni = 0; ni < 4; ++ni) {
    const int n_g = bn * 128 + wc * 64 + ni * 16 + c;
    const int proj = n_g >> 10, ncol = n_g & 1023;
    const float bv = proj == 0 ? bias[ncol] : proj == 1 ? bias2[ncol] : bias3[ncol];
    const int h = ncol >> 6, d = ncol & (D_ - 1);
#pragma unroll
    for (int mi = 0; mi < 4; ++mi) {
#pragma unroll
      for (int r = 0; r < 4; ++r) {
        const int m_g = bm * 128 + wr * 64 + mi * 16 + g * 4 + r;
        const float val = acc[mi][ni][r] + bv;
        const int b = m_g >> 11, s = m_g & (S_ - 1);
        size_t idx = (size_t)proj * 4194304;
        if (proj < 2)
          idx += (((size_t)(b * H_ + h)) * S_ + s) * D_ + d;
        else
          idx += (((size_t)(b * H_ + h)) * D_ + d) * S_ + s;
        out[idx] = __float2bfloat16(val);
      }
    }
  }
}

// ---------------- output projection GEMM (2-phase, 128x64 tile) ----------
__global__ __launch_bounds__(256) void gemm_out_kernel(
    const bf16* __restrict__ A, const bf16* __restrict__ Bt,
    const float* __restrict__ bias, float* __restrict__ out, int K) {
  __shared__ bf16 As[2][128 * 32];
  __shared__ bf16 Bs[2][64 * 32];
  const int tid = threadIdx.x;
  const int wid = tid >> 6, lane = tid & 63;
  const int g = lane >> 4, c = lane & 15;
  const int wr = wid >> 1, wc = wid & 1;
  const int bm = blockIdx.x, bn = blockIdx.y;

  f32x4 acc[4][2] = {};

  const char* Ag = (const char*)(A + (size_t)bm * 128 * K);
  const char* Bg = (const char*)(Bt + (size_t)bn * 64 * K);
  const int s0 = tid, s1 = tid + 256;
  const int ra0 = s0 >> 2, ca0 = (s0 & 3) * 16;
  const int ra1 = s1 >> 2, ca1 = (s1 & 3) * 16;
  const int rb = tid >> 2, cb2 = (tid & 3) * 16;
  const size_t rowbytes = (size_t)K * 2;

  auto stage = [&](int kt, int bufi) {
    const size_t koff = (size_t)kt * 64;
    load16(Ag + (size_t)ra0 * rowbytes + koff + ca0, (char*)As[bufi] + s0 * 16);
    load16(Ag + (size_t)ra1 * rowbytes + koff + ca1, (char*)As[bufi] + s1 * 16);
    load16(Bg + (size_t)rb * rowbytes + koff + cb2, (char*)Bs[bufi] + tid * 16);
  };

  const int NT = K / 32;
  stage(0, 0);
  int cur = 0;
#pragma unroll 1
  for (int kt = 0; kt < NT; ++kt) {
    if (kt + 1 < NT) {
      stage(kt + 1, cur ^ 1);
      asm volatile("s_waitcnt vmcnt(3)" ::: "memory");
    } else {
      asm volatile("s_waitcnt vmcnt(0)" ::: "memory");
    }
    __builtin_amdgcn_s_barrier();

    bf16x8 af[4], bfr[2];
#pragma unroll
    for (int mi = 0; mi < 4; ++mi)
      af[mi] = *(const bf16x8*)&As[cur][(wr * 64 + mi * 16 + c) * 32 + g * 8];
#pragma unroll
    for (int ni = 0; ni < 2; ++ni)
      bfr[ni] = *(const bf16x8*)&Bs[cur][(wc * 32 + ni * 16 + c) * 32 + g * 8];
    __builtin_amdgcn_s_setprio(1);
#pragma unroll
    for (int mi = 0; mi < 4; ++mi)
#pragma unroll
      for (int ni = 0; ni < 2; ++ni)
        acc[mi][ni] = MFMA_BF16(af[mi], bfr[ni], acc[mi][ni]);
    __builtin_amdgcn_s_setprio(0);

    if (kt + 1 < NT) __builtin_amdgcn_s_barrier();
    cur ^= 1;
  }

#pragma unroll
  for (int ni = 0; ni < 2; ++ni) {
    const int n_g = bn * 64 + wc * 32 + ni * 16 + c;
    const float bv = bias[n_g];
#pragma unroll
    for (int mi = 0; mi < 4; ++mi) {
#pragma unroll
      for (int r = 0; r < 4; ++r) {
        const int m_g = bm * 128 + wr * 64 + mi * 16 + g * 4 + r;
        out[(size_t)m_g * DM_ + n_g] = acc[mi][ni][r] + bv;
      }
    }
  }
}

// ---------------- flash attention ----------------
// Q,K: (B,H,S,D) bf16 ; Vt: (B,H,D,S) bf16 ; Aout: (B,S,H*D) bf16
// R15 change (only): TWO adjacent q-tiles per wave (t=base, base+1 — same
// dtile, shared kf/vf fragments). Block = 4 waves covers 8 tiles; grid 512.
// Per staged K/V tile: 2x MFMA + 2 independent softmax chains per wave
// (ILP replaces the halved TLP; chains/CU stays 16); staging traffic and
// barriers per unit compute halve. Body per tile = R13-proven (defer-max
// gate R10, ones-MFMA denom R12). Waves 0-1 run one fully-masked tail iter.
__global__ __launch_bounds__(256, 4) void flash_attn_kernel(
    const bf16* __restrict__ Q, const bf16* __restrict__ Kg,
    const bf16* __restrict__ Vt, bf16* __restrict__ Aout) {
  __shared__ bf16 Ks[2][64 * 64];
  __shared__ bf16 Vs[2][64 * 64];
  const int tid = threadIdx.x;
  const int w = tid >> 6, lane = tid & 63;
  const int g = lane >> 4, c = lane & 15;

  const int bid = blockIdx.x;
  const int xcd = bid & 7, loc = bid >> 3;      // 0..63
  const int bh = xcd * 4 + (loc & 3);
  const int v = 15 - (loc >> 2);                // 0..15, longest first
  const int base = v * 8 + w * 2;               // tiles base, base+1
  const int dtile = base >> 2;                  // same for both tiles
  const int jtop = 2 * v + 1;                   // block kv range 0..jtop
  const int b = bh >> 4, h = bh & (H_ - 1);

  const float ALPHA2 = 0.125f * 1.44269504f;
  const float THR2 = 11.5f;
  const float NEG_INF = -__builtin_inff();

  const char* Kbase = (const char*)(Kg + (size_t)bh * S_ * D_);
  const char* Vbase = (const char*)(Vt + (size_t)bh * D_ * S_);
  const int s0 = tid, s1 = tid + 256;
  const int sr0 = s0 >> 3, sq0 = ((s0 & 7) ^ (sr0 & 7)) << 4;
  const int sr1 = s1 >> 3, sq1 = ((s1 & 7) ^ (sr1 & 7)) << 4;

  const bf16* QpA = Q + ((size_t)bh * S_ + base * 16 + c) * D_;
  bf16x8 qfA0 = *(const bf16x8*)&QpA[g * 8];
  bf16x8 qfA1 = *(const bf16x8*)&QpA[32 + g * 8];
  const bf16* QpB = QpA + 16 * D_;
  bf16x8 qfB0 = *(const bf16x8*)&QpB[g * 8];
  bf16x8 qfB1 = *(const bf16x8*)&QpB[32 + g * 8];

  bf16x8 onesf;
#pragma unroll
  for (int jj = 0; jj < 8; ++jj) onesf[jj] = (short)0x3f80;

  f32x4 oA[4] = {}, oB[4] = {};
  f32x4 laccA = {}, laccB = {};
  float mA = -1000.0f, mB = -1000.0f;

  const int rowlimA = (base & 3) * 16 + c;   // base&3 in {0,2}
  const int rowlimB = rowlimA + 16;
  const int src0 = ((g & 1) * 2) * 16 + c;
  const int src1 = src0 + 16;
  const bool ghi = (g >= 2);
  const int cs = c & 7;
  int roff[2][4];
#pragma unroll
  for (int kk = 0; kk < 2; ++kk)
#pragma unroll
    for (int n = 0; n < 4; ++n)
      roff[kk][n] = n * 2048 + c * 128 + (((kk * 4 + g) ^ cs) << 4);

  {
    load16(Kbase + sr0 * 128 + sq0, (char*)Ks[0] + s0 * 16);
    load16(Kbase + sr1 * 128 + sq1, (char*)Ks[0] + s1 * 16);
    load16(Vbase + sr0 * 4096 + sq0, (char*)Vs[0] + s0 * 16);
    load16(Vbase + sr1 * 4096 + sq1, (char*)Vs[0] + s1 * 16);
  }
  __syncthreads();

  int cur = 0;
#pragma unroll 1
  for (int kv = 0; kv <= jtop; ++kv) {
    if (kv < jtop) {
      const char* Krow = Kbase + (size_t)(kv + 1) * 8192;
      const char* Vcol = Vbase + (size_t)(kv + 1) * 128;
      const int nb = cur ^ 1;
      load16(Krow + sr0 * 128 + sq0, (char*)Ks[nb] + s0 * 16);
      load16(Krow + sr1 * 128 + sq1, (char*)Ks[nb] + s1 * 16);
      load16(Vcol + sr0 * 4096 + sq0, (char*)Vs[nb] + s0 * 16);
      load16(Vcol + sr1 * 4096 + sq1, (char*)Vs[nb] + s1 * 16);
    }

    const char* Kt = (const char*)Ks[cur];
    const char* Vtile = (const char*)Vs[cur];
    bf16x8 kf[2][4];
#pragma unroll
    for (int kk = 0; kk < 2; ++kk)
#pragma unroll
      for (int n = 0; n < 4; ++n)
        kf[kk][n] = *(const bf16x8*)(Kt + roff[kk][n]);

    f32x4 stA[4] = {}, stB[4] = {};
    __builtin_amdgcn_s_setprio(1);
#pragma unroll
    for (int n = 0; n < 4; ++n) {
      stA[n] = MFMA_BF16(kf[0][n], qfA0, stA[n]);
      stA[n] = MFMA_BF16(kf[1][n], qfA1, stA[n]);
      stB[n] = MFMA_BF16(kf[0][n], qfB0, stB[n]);
      stB[n] = MFMA_BF16(kf[1][n], qfB1, stB[n]);
    }
    __builtin_amdgcn_s_setprio(0);

    bf16x8 vf[2][4];
#pragma unroll
    for (int kk = 0; kk < 2; ++kk)
#pragma unroll
      for (int n = 0; n < 4; ++n)
        vf[kk][n] = *(const bf16x8*)(Vtile + roff[kk][n]);

    const bool onDiag = (kv >= dtile);

    // ---- tile A softmax (in-register, defer-max gated) ----
    float pA[4][4];
    {
      float aa[4][4];
#pragma unroll
      for (int n = 0; n < 4; ++n)
#pragma unroll
        for (int r = 0; r < 4; ++r)
          aa[n][r] = fmaf(stA[n][r], ALPHA2, -mA);
      if (onDiag) {
        const int lim = (kv == dtile) ? rowlimA : -1;
#pragma unroll
        for (int n = 0; n < 4; ++n)
#pragma unroll
          for (int r = 0; r < 4; ++r)
            if (n * 16 + g * 4 + r > lim) aa[n][r] = NEG_INF;
      }
      float lm;
      {
        float t0 = fmaxf(fmaxf(aa[0][0], aa[0][1]), fmaxf(aa[0][2], aa[0][3]));
        float t1 = fmaxf(fmaxf(aa[1][0], aa[1][1]), fmaxf(aa[1][2], aa[1][3]));
        float t2 = fmaxf(fmaxf(aa[2][0], aa[2][1]), fmaxf(aa[2][2], aa[2][3]));
        float t3 = fmaxf(fmaxf(aa[3][0], aa[3][1]), fmaxf(aa[3][2], aa[3][3]));
        lm = fmaxf(fmaxf(t0, t1), fmaxf(t2, t3));
      }
      if (__any(lm > THR2)) {
        float dm = fmaxf(lm, __shfl_xor(lm, 16, 64));
        dm = fmaxf(dm, __shfl_xor(dm, 32, 64));
        const float sh = fmaxf(dm, 0.0f);
        const float sc = __builtin_amdgcn_exp2f(-sh);
        mA += sh;
#pragma unroll
        for (int r = 0; r < 4; ++r) laccA[r] *= sc;
#pragma unroll
        for (int n = 0; n < 4; ++n)
#pragma unroll
          for (int r = 0; r < 4; ++r) oA[n][r] *= sc;
#pragma unroll
        for (int n = 0; n < 4; ++n)
#pragma unroll
          for (int r = 0; r < 4; ++r) aa[n][r] -= sh;
      }
#pragma unroll
      for (int n = 0; n < 4; ++n)
#pragma unroll
        for (int r = 0; r < 4; ++r) pA[n][r] = __builtin_amdgcn_exp2f(aa[n][r]);
    }

    // ---- tile B softmax ----
    float pB[4][4];
    {
      float aa[4][4];
#pragma unroll
      for (int n = 0; n < 4; ++n)
#pragma unroll
        for (int r = 0; r < 4; ++r)
          aa[n][r] = fmaf(stB[n][r], ALPHA2, -mB);
      if (onDiag) {
        const int lim = (kv == dtile) ? rowlimB : -1;
#pragma unroll
        for (int n = 0; n < 4; ++n)
#pragma unroll
          for (int r = 0; r < 4; ++r)
            if (n * 16 + g * 4 + r > lim) aa[n][r] = NEG_INF;
      }
      float lm;
      {
        float t0 = fmaxf(fmaxf(aa[0][0], aa[0][1]), fmaxf(aa[0][2], aa[0][3]));
        float t1 = fmaxf(fmaxf(aa[1][0], aa[1][1]), fmaxf(aa[1][2], aa[1][3]));
        float t2 = fmaxf(fmaxf(aa[2][0], aa[2][1]), fmaxf(aa[2][2], aa[2][3]));
        float t3 = fmaxf(fmaxf(aa[3][0], aa[3][1]), fmaxf(aa[3][2], aa[3][3]));
        lm = fmaxf(fmaxf(t0, t1), fmaxf(t2, t3));
      }
      if (__any(lm > THR2)) {
        float dm = fmaxf(lm, __shfl_xor(lm, 16, 64));
        dm = fmaxf(dm, __shfl_xor(dm, 32, 64));
        const float sh = fmaxf(dm, 0.0f);
        const float sc = __builtin_amdgcn_exp2f(-sh);
        mB += sh;
#pragma unroll
        for (int r = 0; r < 4; ++r) laccB[r] *= sc;
#pragma unroll
        for (int n = 0; n < 4; ++n)
#pragma unroll
          for (int r = 0; r < 4; ++r) oB[n][r] *= sc;
#pragma unroll
        for (int n = 0; n < 4; ++n)
#pragma unroll
          for (int r = 0; r < 4; ++r) aa[n][r] -= sh;
      }
#pragma unroll
      for (int n = 0; n < 4; ++n)
#pragma unroll
        for (int r = 0; r < 4; ++r) pB[n][r] = __builtin_amdgcn_exp2f(aa[n][r]);
    }

    unsigned int dwA[4][2], dwB[4][2];
#pragma unroll
    for (int n = 0; n < 4; ++n) {
      dwA[n][0] = pack_bf16(pA[n][0], pA[n][1]);
      dwA[n][1] = pack_bf16(pA[n][2], pA[n][3]);
      dwB[n][0] = pack_bf16(pB[n][0], pB[n][1]);
      dwB[n][1] = pack_bf16(pB[n][2], pB[n][3]);
    }

    // ---- transpose + PV, tile A then tile B (shared vf) ----
#pragma unroll
    for (int kk = 0; kk < 2; ++kk) {
      unsigned int bb[4];
      {
        unsigned int lo = __shfl(dwA[kk * 2][0], src0, 64);
        unsigned int hi = __shfl(dwA[kk * 2 + 1][0], src0, 64);
        bb[0] = ghi ? hi : lo;
      }
      {
        unsigned int lo = __shfl(dwA[kk * 2][1], src0, 64);
        unsigned int hi = __shfl(dwA[kk * 2 + 1][1], src0, 64);
        bb[1] = ghi ? hi : lo;
      }
      {
        unsigned int lo = __shfl(dwA[kk * 2][0], src1, 64);
        unsigned int hi = __shfl(dwA[kk * 2 + 1][0], src1, 64);
        bb[2] = ghi ? hi : lo;
      }
      {
        unsigned int lo = __shfl(dwA[kk * 2][1], src1, 64);
        unsigned int hi = __shfl(dwA[kk * 2 + 1][1], src1, 64);
        bb[3] = ghi ? hi : lo;
      }
      u32x4 bbv = {bb[0], bb[1], bb[2], bb[3]};
      bf16x8 pb = __builtin_bit_cast(bf16x8, bbv);
      __builtin_amdgcn_s_setprio(1);
#pragma unroll
      for (int n = 0; n < 4; ++n) oA[n] = MFMA_BF16(vf[kk][n], pb, oA[n]);
      laccA = MFMA_BF16(onesf, pb, laccA);
      __builtin_amdgcn_s_setprio(0);
    }
#pragma unroll
    for (int kk = 0; kk < 2; ++kk) {
      unsigned int bb[4];
      {
        unsigned int lo = __shfl(dwB[kk * 2][0], src0, 64);
        unsigned int hi = __shfl(dwB[kk * 2 + 1][0], src0, 64);
        bb[0] = ghi ? hi : lo;
      }
      {
        unsigned int lo = __shfl(dwB[kk * 2][1], src0, 64);
        unsigned int hi = __shfl(dwB[kk * 2 + 1][1], src0, 64);
        bb[1] = ghi ? hi : lo;
      }
      {
        unsigned int lo = __shfl(dwB[kk * 2][0], src1, 64);
        unsigned int hi = __shfl(dwB[kk * 2 + 1][0], src1, 64);
        bb[2] = ghi ? hi : lo;
      }
      {
        unsigned int lo = __shfl(dwB[kk * 2][1], src1, 64);
        unsigned int hi = __shfl(dwB[kk * 2 + 1][1], src1, 64);
        bb[3] = ghi ? hi : lo;
      }
      u32x4 bbv = {bb[0], bb[1], bb[2], bb[3]};
      bf16x8 pb = __builtin_bit_cast(bf16x8, bbv);
      __builtin_amdgcn_s_setprio(1);
#pragma unroll
      for (int n = 0; n < 4; ++n) oB[n] = MFMA_BF16(vf[kk][n], pb, oB[n]);
      laccB = MFMA_BF16(onesf, pb, laccB);
      __builtin_amdgcn_s_setprio(0);
    }

    __syncthreads();
    cur ^= 1;
  }

  const float invA = 1.0f / laccA[0];
  bf16* ArowA = Aout + ((size_t)b * S_ + base * 16 + c) * (H_ * D_) + h * D_;
#pragma unroll
  for (int n = 0; n < 4; ++n) {
    ushort4 u2;
    u2.x = __builtin_bit_cast(unsigned short, __float2bfloat16(oA[n][0] * invA));
    u2.y = __builtin_bit_cast(unsigned short, __float2bfloat16(oA[n][1] * invA));
    u2.z = __builtin_bit_cast(unsigned short, __float2bfloat16(oA[n][2] * invA));
    u2.w = __builtin_bit_cast(unsigned short, __float2bfloat16(oA[n][3] * invA));
    *(ushort4*)&ArowA[n * 16 + g * 4] = u2;
  }
  const float invB = 1.0f / laccB[0];
  bf16* ArowB = ArowA + (size_t)16 * (H_ * D_);
#pragma unroll
  for (int n = 0; n < 4; ++n) {
    ushort4 u2;
    u2.x = __builtin_bit_cast(unsigned short, __float2bfloat16(oB[n][0] * invB));
    u2.y = __builtin_bit_cast(unsigned short, __float2bfloat16(oB[n][1] * invB));
    u2.z = __builtin_bit_cast(unsigned short, __float2bfloat16(oB[n][2] * invB));
    u2.w = __builtin_bit_cast(unsigned short, __float2bfloat16(oB[n][3] * invB));
    *(ushort4*)&ArowB[n * 16 + g * 4] = u2;
  }
}

// ---------------- launcher ----------------

extern "C" void kernel_launch(void* const* d_in, const int* in_sizes, int n_in,
                              void* d_out, int out_size, void* d_ws, size_t ws_size,
                              hipStream_t stream) {
  (void)in_sizes; (void)n_in; (void)out_size; (void)ws_size;
  const float* x  = (const float*)d_in[0];
  const float* Wq = (const float*)d_in[1];
  const float* bq = (const float*)d_in[2];
  const float* Wk = (const float*)d_in[3];
  const float* bk = (const float*)d_in[4];
  const float* Wv = (const float*)d_in[5];
  const float* bv = (const float*)d_in[6];
  const float* Wo = (const float*)d_in[7];
  const float* bo = (const float*)d_in[8];
  float* out = (float*)d_out;

  char* ws = (char*)d_ws;
  bf16* xb  = (bf16*)(ws);                    // 8 MB  (4096x1024 bf16)
  bf16* Wqt = (bf16*)(ws + (8u << 20));       // 2 MB each, CONTIGUOUS (QKV fused)
  bf16* Wkt = (bf16*)(ws + (10u << 20));
  bf16* Wvt = (bf16*)(ws + (12u << 20));
  bf16* Wot = (bf16*)(ws + (14u << 20));
  bf16* Qb  = (bf16*)(ws + (16u << 20));      // 8 MB  (B,H,S,D)  -- +0*4194304
  bf16* Kb  = (bf16*)(ws + (24u << 20));      // 8 MB             -- +1*4194304
  bf16* Vtb = (bf16*)(ws + (32u << 20));      // 8 MB  (B,H,D,S)  -- +2*4194304
  bf16* Ab  = xb;  // attention out reuses xb (xb dead after projections)

  prep_kernel<<<dim3(32, 32, 5), 256, 0, stream>>>(
      Wq, Wk, Wv, Wo, x, Wqt, Wkt, Wvt, Wot, xb);

  // fused QKV projection: Bt = [Wqt;Wkt;Wvt] (3072 rows), 2-phase 128^2
  gemm_qkv_kernel<<<dim3(32, 24), 256, 0, stream>>>(
      xb, Wqt, bq, bk, bv, Qb, DM_);

  flash_attn_kernel<<<dim3(512), 256, 0, stream>>>(Qb, Kb, Vtb, Ab);

  gemm_out_kernel<<<dim3(32, 16), 256, 0, stream>>>(Ab, Wot, bo, out, DM_);
}

// Round 17
// 127.443 us; speedup vs baseline: 1.3135x; 1.3135x over previous
//
#include <hip/hip_runtime.h>
#include <hip/hip_bf16.h>

typedef __hip_bfloat16 bf16;
typedef __attribute__((ext_vector_type(8))) short bf16x8;
typedef __attribute__((ext_vector_type(4))) float f32x4;
typedef __attribute__((ext_vector_type(4))) unsigned int u32x4;

#define MFMA_BF16(a, b, c) __builtin_amdgcn_mfma_f32_16x16x32_bf16((a), (b), (c), 0, 0, 0)

static constexpr int B_  = 2;
static constexpr int S_  = 2048;
static constexpr int DM_ = 1024;
static constexpr int H_  = 16;
static constexpr int D_  = 64;
static constexpr int M_  = B_ * S_;   // 4096 rows for all GEMMs

__device__ __forceinline__ void load16(const void* g, void* l) {
  __builtin_amdgcn_global_load_lds(
      (const __attribute__((address_space(1))) void*)g,
      (__attribute__((address_space(3))) void*)l, 16, 0, 0);
}

__device__ __forceinline__ unsigned int pack_bf16(float lo, float hi) {
  const unsigned int ul = __builtin_bit_cast(unsigned short, __float2bfloat16(lo));
  const unsigned int uh = __builtin_bit_cast(unsigned short, __float2bfloat16(hi));
  return (uh << 16) | ul;
}

// ---------------- fused prep: 4x weight transpose + x cvt ----------------
__global__ void prep_kernel(const float* __restrict__ w0,
                            const float* __restrict__ w1,
                            const float* __restrict__ w2,
                            const float* __restrict__ w3,
                            const float* __restrict__ x,
                            bf16* __restrict__ o0, bf16* __restrict__ o1,
                            bf16* __restrict__ o2, bf16* __restrict__ o3,
                            bf16* __restrict__ xb) {
  if (blockIdx.z == 4) {
    const int blk = blockIdx.y * 32 + blockIdx.x;   // 0..1023
#pragma unroll
    for (int rep = 0; rep < 4; ++rep) {
      const int i = blk * 1024 + rep * 256 + threadIdx.x;  // float4 index
      float4 v = ((const float4*)x)[i];
      ushort4 u;
      u.x = __builtin_bit_cast(unsigned short, __float2bfloat16(v.x));
      u.y = __builtin_bit_cast(unsigned short, __float2bfloat16(v.y));
      u.z = __builtin_bit_cast(unsigned short, __float2bfloat16(v.z));
      u.w = __builtin_bit_cast(unsigned short, __float2bfloat16(v.w));
      ((ushort4*)xb)[i] = u;
    }
    return;
  }
  __shared__ float t[32][33];
  const float* in = blockIdx.z == 0 ? w0 : blockIdx.z == 1 ? w1 : blockIdx.z == 2 ? w2 : w3;
  bf16* out = blockIdx.z == 0 ? o0 : blockIdx.z == 1 ? o1 : blockIdx.z == 2 ? o2 : o3;
  int tx = threadIdx.x & 31;
  int ty = threadIdx.x >> 5;  // 0..7
  int r0 = blockIdx.y * 32;
  int c0 = blockIdx.x * 32;
#pragma unroll
  for (int yy = 0; yy < 32; yy += 8)
    t[ty + yy][tx] = in[(size_t)(r0 + ty + yy) * DM_ + c0 + tx];
  __syncthreads();
#pragma unroll
  for (int yy = 0; yy < 32; yy += 8)
    out[(size_t)(c0 + ty + yy) * DM_ + r0 + tx] = __float2bfloat16(t[tx][ty + yy]);
}

// ---------------- QKV GEMM (2-phase, 128x128, proven; R16: +XCD swizzle) --
__global__ __launch_bounds__(256) void gemm_qkv_kernel(
    const bf16* __restrict__ A, const bf16* __restrict__ Bt,
    const float* __restrict__ bias, const float* __restrict__ bias2,
    const float* __restrict__ bias3, bf16* __restrict__ out, int K) {
  __shared__ bf16 As[2][128 * 32];
  __shared__ bf16 Bs[2][128 * 32];
  const int tid = threadIdx.x;
  const int wid = tid >> 6, lane = tid & 63;
  const int g = lane >> 4, c = lane & 15;
  const int wr = wid >> 1, wc = wid & 1;
  // T1 XCD swizzle: 768 blocks = 8 XCDs x 96; each XCD's co-resident chunk
  // covers 3 complete bn panels -> per-XCD L2 B-traffic /8. Bijective.
  const int flat = blockIdx.y * 32 + blockIdx.x;
  const int swz = (flat & 7) * 96 + (flat >> 3);
  const int bm = swz & 31, bn = swz >> 5;

  f32x4 acc[4][4] = {};

  const char* Ag = (const char*)(A + (size_t)bm * 128 * K);
  const char* Bg = (const char*)(Bt + (size_t)bn * 128 * K);
  const int f0 = tid * 16, f1 = f0 + 4096;
  const int r0 = f0 >> 6, cb0 = f0 & 63;
  const int r1 = f1 >> 6;
  const size_t rowbytes = (size_t)K * 2;

  auto stage = [&](int kt, int bufi) {
    const size_t koff = (size_t)kt * 64;
    load16(Ag + (size_t)r0 * rowbytes + koff + cb0, (char*)As[bufi] + f0);
    load16(Ag + (size_t)r1 * rowbytes + koff + cb0, (char*)As[bufi] + f1);
    load16(Bg + (size_t)r0 * rowbytes + koff + cb0, (char*)Bs[bufi] + f0);
    load16(Bg + (size_t)r1 * rowbytes + koff + cb0, (char*)Bs[bufi] + f1);
  };

  const int NT = K / 32;
  stage(0, 0);
  int cur = 0;
#pragma unroll 1
  for (int kt = 0; kt < NT; ++kt) {
    if (kt + 1 < NT) {
      stage(kt + 1, cur ^ 1);
      asm volatile("s_waitcnt vmcnt(4)" ::: "memory");
    } else {
      asm volatile("s_waitcnt vmcnt(0)" ::: "memory");
    }
    __builtin_amdgcn_s_barrier();

    bf16x8 af[4], bfr[4];
#pragma unroll
    for (int mi = 0; mi < 4; ++mi)
      af[mi] = *(const bf16x8*)&As[cur][(wr * 64 + mi * 16 + c) * 32 + g * 8];
#pragma unroll
    for (int ni = 0; ni < 4; ++ni)
      bfr[ni] = *(const bf16x8*)&Bs[cur][(wc * 64 + ni * 16 + c) * 32 + g * 8];
    __builtin_amdgcn_s_setprio(1);
#pragma unroll
    for (int mi = 0; mi < 4; ++mi)
#pragma unroll
      for (int ni = 0; ni < 4; ++ni)
        acc[mi][ni] = MFMA_BF16(af[mi], bfr[ni], acc[mi][ni]);
    __builtin_amdgcn_s_setprio(0);

    if (kt + 1 < NT) __builtin_amdgcn_s_barrier();
    cur ^= 1;
  }

#pragma unroll
  for (int ni = 0; ni < 4; ++ni) {
    const int n_g = bn * 128 + wc * 64 + ni * 16 + c;
    const int proj = n_g >> 10, ncol = n_g & 1023;
    const float bv = proj == 0 ? bias[ncol] : proj == 1 ? bias2[ncol] : bias3[ncol];
    const int h = ncol >> 6, d = ncol & (D_ - 1);
#pragma unroll
    for (int mi = 0; mi < 4; ++mi) {
#pragma unroll
      for (int r = 0; r < 4; ++r) {
        const int m_g = bm * 128 + wr * 64 + mi * 16 + g * 4 + r;
        const float val = acc[mi][ni][r] + bv;
        const int b = m_g >> 11, s = m_g & (S_ - 1);
        size_t idx = (size_t)proj * 4194304;
        if (proj < 2)
          idx += (((size_t)(b * H_ + h)) * S_ + s) * D_ + d;
        else
          idx += (((size_t)(b * H_ + h)) * D_ + d) * S_ + s;
        out[idx] = __float2bfloat16(val);
      }
    }
  }
}

// ---------------- output projection GEMM (2-phase, 128x64; +XCD swizzle) --
__global__ __launch_bounds__(256) void gemm_out_kernel(
    const bf16* __restrict__ A, const bf16* __restrict__ Bt,
    const float* __restrict__ bias, float* __restrict__ out, int K) {
  __shared__ bf16 As[2][128 * 32];
  __shared__ bf16 Bs[2][64 * 32];
  const int tid = threadIdx.x;
  const int wid = tid >> 6, lane = tid & 63;
  const int g = lane >> 4, c = lane & 15;
  const int wr = wid >> 1, wc = wid & 1;
  // T1 XCD swizzle: 512 blocks = 8 x 64 (2 bn panels per XCD chunk)
  const int flat = blockIdx.y * 32 + blockIdx.x;
  const int swz = (flat & 7) * 64 + (flat >> 3);
  const int bm = swz & 31, bn = swz >> 5;

  f32x4 acc[4][2] = {};

  const char* Ag = (const char*)(A + (size_t)bm * 128 * K);
  const char* Bg = (const char*)(Bt + (size_t)bn * 64 * K);
  const int s0 = tid, s1 = tid + 256;
  const int ra0 = s0 >> 2, ca0 = (s0 & 3) * 16;
  const int ra1 = s1 >> 2, ca1 = (s1 & 3) * 16;
  const int rb = tid >> 2, cb2 = (tid & 3) * 16;
  const size_t rowbytes = (size_t)K * 2;

  auto stage = [&](int kt, int bufi) {
    const size_t koff = (size_t)kt * 64;
    load16(Ag + (size_t)ra0 * rowbytes + koff + ca0, (char*)As[bufi] + s0 * 16);
    load16(Ag + (size_t)ra1 * rowbytes + koff + ca1, (char*)As[bufi] + s1 * 16);
    load16(Bg + (size_t)rb * rowbytes + koff + cb2, (char*)Bs[bufi] + tid * 16);
  };

  const int NT = K / 32;
  stage(0, 0);
  int cur = 0;
#pragma unroll 1
  for (int kt = 0; kt < NT; ++kt) {
    if (kt + 1 < NT) {
      stage(kt + 1, cur ^ 1);
      asm volatile("s_waitcnt vmcnt(3)" ::: "memory");
    } else {
      asm volatile("s_waitcnt vmcnt(0)" ::: "memory");
    }
    __builtin_amdgcn_s_barrier();

    bf16x8 af[4], bfr[2];
#pragma unroll
    for (int mi = 0; mi < 4; ++mi)
      af[mi] = *(const bf16x8*)&As[cur][(wr * 64 + mi * 16 + c) * 32 + g * 8];
#pragma unroll
    for (int ni = 0; ni < 2; ++ni)
      bfr[ni] = *(const bf16x8*)&Bs[cur][(wc * 32 + ni * 16 + c) * 32 + g * 8];
    __builtin_amdgcn_s_setprio(1);
#pragma unroll
    for (int mi = 0; mi < 4; ++mi)
#pragma unroll
      for (int ni = 0; ni < 2; ++ni)
        acc[mi][ni] = MFMA_BF16(af[mi], bfr[ni], acc[mi][ni]);
    __builtin_amdgcn_s_setprio(0);

    if (kt + 1 < NT) __builtin_amdgcn_s_barrier();
    cur ^= 1;
  }

#pragma unroll
  for (int ni = 0; ni < 2; ++ni) {
    const int n_g = bn * 64 + wc * 32 + ni * 16 + c;
    const float bv = bias[n_g];
#pragma unroll
    for (int mi = 0; mi < 4; ++mi) {
#pragma unroll
      for (int r = 0; r < 4; ++r) {
        const int m_g = bm * 128 + wr * 64 + mi * 16 + g * 4 + r;
        out[(size_t)m_g * DM_ + n_g] = acc[mi][ni][r] + bv;
      }
    }
  }
}

// ---------------- flash attention (R13-proven, byte-identical) -----------
// Q,K: (B,H,S,D) bf16 ; Vt: (B,H,D,S) bf16 ; Aout: (B,S,H*D) bf16
// Block = 4 waves = one t-quad of one bh; double-buffered XOR-swizzled LDS
// (__syncthreads pipeline). Swapped-QK^T in-register softmax, defer-max
// gate on per-lane local max (R10), l via ones-MFMA (R12), balanced
// quad->CU mapping (R13). CONFIRMED LOCAL OPTIMUM: R4/R6/R7/R9/R14/R15
// perturbations (pairing, kv-split, half-quads, counted vmcnt, 8-wave
// merge, 2-tile ILP) all neutral-or-worse.
__global__ __launch_bounds__(256, 4) void flash_attn_kernel(
    const bf16* __restrict__ Q, const bf16* __restrict__ Kg,
    const bf16* __restrict__ Vt, bf16* __restrict__ Aout) {
  __shared__ bf16 Ks[2][64 * 64];
  __shared__ bf16 Vs[2][64 * 64];
  const int tid = threadIdx.x;
  const int w = tid >> 6, lane = tid & 63;
  const int g = lane >> 4, c = lane & 15;

  const int bid = blockIdx.x;
  const int xcd = bid & 7, loc = bid >> 3;
  const int bh = xcd * 4 + (loc & 3);
  const int u = loc >> 2;                 // 0..31
  const int slot = u >> 3, q = u & 7;
  const int j = slot == 0 ? 31 - q : slot == 1 ? 16 + q
              : slot == 2 ? 15 - q : q;   // balanced: per-CU sum = 62
  const int t = j * 4 + w;
  const int b = bh >> 4, h = bh & (H_ - 1);

  const float ALPHA2 = 0.125f * 1.44269504f;
  const float THR2 = 11.5f;
  const float NEG_INF = -__builtin_inff();

  const char* Kbase = (const char*)(Kg + (size_t)bh * S_ * D_);
  const char* Vbase = (const char*)(Vt + (size_t)bh * D_ * S_);
  const int s0 = tid, s1 = tid + 256;
  const int sr0 = s0 >> 3, sq0 = ((s0 & 7) ^ (sr0 & 7)) << 4;
  const int sr1 = s1 >> 3, sq1 = ((s1 & 7) ^ (sr1 & 7)) << 4;

  const bf16* Qp = Q + ((size_t)bh * S_ + t * 16 + c) * D_;
  bf16x8 qf[2];
  qf[0] = *(const bf16x8*)&Qp[g * 8];
  qf[1] = *(const bf16x8*)&Qp[32 + g * 8];

  bf16x8 onesf;
#pragma unroll
  for (int jj = 0; jj < 8; ++jj) onesf[jj] = (short)0x3f80;

  f32x4 o[4] = {};
  f32x4 lacc = {};
  float m = -1000.0f;

  const int rowlim = w * 16 + c;
  const int src0 = ((g & 1) * 2) * 16 + c;
  const int src1 = src0 + 16;
  const bool ghi = (g >= 2);
  const int cs = c & 7;
  int roff[2][4];
#pragma unroll
  for (int kk = 0; kk < 2; ++kk)
#pragma unroll
    for (int n = 0; n < 4; ++n)
      roff[kk][n] = n * 2048 + c * 128 + (((kk * 4 + g) ^ cs) << 4);

  {
    load16(Kbase + sr0 * 128 + sq0, (char*)Ks[0] + s0 * 16);
    load16(Kbase + sr1 * 128 + sq1, (char*)Ks[0] + s1 * 16);
    load16(Vbase + sr0 * 4096 + sq0, (char*)Vs[0] + s0 * 16);
    load16(Vbase + sr1 * 4096 + sq1, (char*)Vs[0] + s1 * 16);
  }
  __syncthreads();

  int cur = 0;
#pragma unroll 1
  for (int kv = 0; kv <= j; ++kv) {
    if (kv < j) {
      const char* Krow = Kbase + (size_t)(kv + 1) * 8192;
      const char* Vcol = Vbase + (size_t)(kv + 1) * 128;
      const int nb = cur ^ 1;
      load16(Krow + sr0 * 128 + sq0, (char*)Ks[nb] + s0 * 16);
      load16(Krow + sr1 * 128 + sq1, (char*)Ks[nb] + s1 * 16);
      load16(Vcol + sr0 * 4096 + sq0, (char*)Vs[nb] + s0 * 16);
      load16(Vcol + sr1 * 4096 + sq1, (char*)Vs[nb] + s1 * 16);
    }

    const char* Kt = (const char*)Ks[cur];
    const char* Vtile = (const char*)Vs[cur];
    bf16x8 kf[2][4];
#pragma unroll
    for (int kk = 0; kk < 2; ++kk)
#pragma unroll
      for (int n = 0; n < 4; ++n)
        kf[kk][n] = *(const bf16x8*)(Kt + roff[kk][n]);

    f32x4 st[4] = {};
    __builtin_amdgcn_s_setprio(1);
#pragma unroll
    for (int n = 0; n < 4; ++n) {
      st[n] = MFMA_BF16(kf[0][n], qf[0], st[n]);
      st[n] = MFMA_BF16(kf[1][n], qf[1], st[n]);
    }
    __builtin_amdgcn_s_setprio(0);

    bf16x8 vf[2][4];
#pragma unroll
    for (int kk = 0; kk < 2; ++kk)
#pragma unroll
      for (int n = 0; n < 4; ++n)
        vf[kk][n] = *(const bf16x8*)(Vtile + roff[kk][n]);

    float aa[4][4];
#pragma unroll
    for (int n = 0; n < 4; ++n)
#pragma unroll
      for (int r = 0; r < 4; ++r)
        aa[n][r] = fmaf(st[n][r], ALPHA2, -m);
    if (kv == j) {
#pragma unroll
      for (int n = 0; n < 4; ++n)
#pragma unroll
        for (int r = 0; r < 4; ++r)
          if (n * 16 + g * 4 + r > rowlim) aa[n][r] = NEG_INF;
    }

    float lm;
    {
      float t0 = fmaxf(fmaxf(aa[0][0], aa[0][1]), fmaxf(aa[0][2], aa[0][3]));
      float t1 = fmaxf(fmaxf(aa[1][0], aa[1][1]), fmaxf(aa[1][2], aa[1][3]));
      float t2 = fmaxf(fmaxf(aa[2][0], aa[2][1]), fmaxf(aa[2][2], aa[2][3]));
      float t3 = fmaxf(fmaxf(aa[3][0], aa[3][1]), fmaxf(aa[3][2], aa[3][3]));
      lm = fmaxf(fmaxf(t0, t1), fmaxf(t2, t3));
    }

    if (__any(lm > THR2)) {
      float dm = fmaxf(lm, __shfl_xor(lm, 16, 64));
      dm = fmaxf(dm, __shfl_xor(dm, 32, 64));
      const float sh = fmaxf(dm, 0.0f);
      const float sc = __builtin_amdgcn_exp2f(-sh);
      m += sh;
#pragma unroll
      for (int r = 0; r < 4; ++r) lacc[r] *= sc;
#pragma unroll
      for (int n = 0; n < 4; ++n)
#pragma unroll
        for (int r = 0; r < 4; ++r) o[n][r] *= sc;
#pragma unroll
      for (int n = 0; n < 4; ++n)
#pragma unroll
        for (int r = 0; r < 4; ++r) aa[n][r] -= sh;
    }

    float p[4][4];
#pragma unroll
    for (int n = 0; n < 4; ++n)
#pragma unroll
      for (int r = 0; r < 4; ++r) p[n][r] = __builtin_amdgcn_exp2f(aa[n][r]);

    unsigned int dw[4][2];
#pragma unroll
    for (int n = 0; n < 4; ++n) {
      dw[n][0] = pack_bf16(p[n][0], p[n][1]);
      dw[n][1] = pack_bf16(p[n][2], p[n][3]);
    }

#pragma unroll
    for (int kk = 0; kk < 2; ++kk) {
      unsigned int bb[4];
      {
        unsigned int lo = __shfl(dw[kk * 2][0], src0, 64);
        unsigned int hi = __shfl(dw[kk * 2 + 1][0], src0, 64);
        bb[0] = ghi ? hi : lo;
      }
      {
        unsigned int lo = __shfl(dw[kk * 2][1], src0, 64);
        unsigned int hi = __shfl(dw[kk * 2 + 1][1], src0, 64);
        bb[1] = ghi ? hi : lo;
      }
      {
        unsigned int lo = __shfl(dw[kk * 2][0], src1, 64);
        unsigned int hi = __shfl(dw[kk * 2 + 1][0], src1, 64);
        bb[2] = ghi ? hi : lo;
      }
      {
        unsigned int lo = __shfl(dw[kk * 2][1], src1, 64);
        unsigned int hi = __shfl(dw[kk * 2 + 1][1], src1, 64);
        bb[3] = ghi ? hi : lo;
      }
      u32x4 bbv = {bb[0], bb[1], bb[2], bb[3]};
      bf16x8 pb = __builtin_bit_cast(bf16x8, bbv);
      __builtin_amdgcn_s_setprio(1);
#pragma unroll
      for (int n = 0; n < 4; ++n) o[n] = MFMA_BF16(vf[kk][n], pb, o[n]);
      lacc = MFMA_BF16(onesf, pb, lacc);
      __builtin_amdgcn_s_setprio(0);
    }

    __syncthreads();
    cur ^= 1;
  }

  const float inv = 1.0f / lacc[0];

  bf16* Arow = Aout + ((size_t)b * S_ + t * 16 + c) * (H_ * D_) + h * D_;
#pragma unroll
  for (int n = 0; n < 4; ++n) {
    ushort4 u2;
    u2.x = __builtin_bit_cast(unsigned short, __float2bfloat16(o[n][0] * inv));
    u2.y = __builtin_bit_cast(unsigned short, __float2bfloat16(o[n][1] * inv));
    u2.z = __builtin_bit_cast(unsigned short, __float2bfloat16(o[n][2] * inv));
    u2.w = __builtin_bit_cast(unsigned short, __float2bfloat16(o[n][3] * inv));
    *(ushort4*)&Arow[n * 16 + g * 4] = u2;
  }
}

// ---------------- launcher ----------------

extern "C" void kernel_launch(void* const* d_in, const int* in_sizes, int n_in,
                              void* d_out, int out_size, void* d_ws, size_t ws_size,
                              hipStream_t stream) {
  (void)in_sizes; (void)n_in; (void)out_size; (void)ws_size;
  const float* x  = (const float*)d_in[0];
  const float* Wq = (const float*)d_in[1];
  const float* bq = (const float*)d_in[2];
  const float* Wk = (const float*)d_in[3];
  const float* bk = (const float*)d_in[4];
  const float* Wv = (const float*)d_in[5];
  const float* bv = (const float*)d_in[6];
  const float* Wo = (const float*)d_in[7];
  const float* bo = (const float*)d_in[8];
  float* out = (float*)d_out;

  char* ws = (char*)d_ws;
  bf16* xb  = (bf16*)(ws);                    // 8 MB  (4096x1024 bf16)
  bf16* Wqt = (bf16*)(ws + (8u << 20));       // 2 MB each, CONTIGUOUS (QKV fused)
  bf16* Wkt = (bf16*)(ws + (10u << 20));
  bf16* Wvt = (bf16*)(ws + (12u << 20));
  bf16* Wot = (bf16*)(ws + (14u << 20));
  bf16* Qb  = (bf16*)(ws + (16u << 20));      // 8 MB  (B,H,S,D)  -- +0*4194304
  bf16* Kb  = (bf16*)(ws + (24u << 20));      // 8 MB             -- +1*4194304
  bf16* Vtb = (bf16*)(ws + (32u << 20));      // 8 MB  (B,H,D,S)  -- +2*4194304
  bf16* Ab  = xb;  // attention out reuses xb (xb dead after projections)

  prep_kernel<<<dim3(32, 32, 5), 256, 0, stream>>>(
      Wq, Wk, Wv, Wo, x, Wqt, Wkt, Wvt, Wot, xb);

  // fused QKV projection: Bt = [Wqt;Wkt;Wvt] (3072 rows), 2-phase 128^2
  gemm_qkv_kernel<<<dim3(32, 24), 256, 0, stream>>>(
      xb, Wqt, bq, bk, bv, Qb, DM_);

  flash_attn_kernel<<<dim3(1024), 256, 0, stream>>>(Qb, Kb, Vtb, Ab);

  gemm_out_kernel<<<dim3(32, 16), 256, 0, stream>>>(Ab, Wot, bo, out, DM_);
}

// Round 18
// 113.244 us; speedup vs baseline: 1.4782x; 1.1254x over previous
//
#include <hip/hip_runtime.h>
#include <hip/hip_bf16.h>

typedef __hip_bfloat16 bf16;
typedef __attribute__((ext_vector_type(8))) short bf16x8;
typedef __attribute__((ext_vector_type(4))) float f32x4;
typedef __attribute__((ext_vector_type(4))) unsigned int u32x4;

#define MFMA_BF16(a, b, c) __builtin_amdgcn_mfma_f32_16x16x32_bf16((a), (b), (c), 0, 0, 0)

static constexpr int B_  = 2;
static constexpr int S_  = 2048;
static constexpr int DM_ = 1024;
static constexpr int H_  = 16;
static constexpr int D_  = 64;
static constexpr int M_  = B_ * S_;   // 4096 rows for all GEMMs

__device__ __forceinline__ void load16(const void* g, void* l) {
  __builtin_amdgcn_global_load_lds(
      (const __attribute__((address_space(1))) void*)g,
      (__attribute__((address_space(3))) void*)l, 16, 0, 0);
}

__device__ __forceinline__ unsigned int pack_bf16(float lo, float hi) {
  const unsigned int ul = __builtin_bit_cast(unsigned short, __float2bfloat16(lo));
  const unsigned int uh = __builtin_bit_cast(unsigned short, __float2bfloat16(hi));
  return (uh << 16) | ul;
}

// ---------------- fused prep: 4x weight transpose + x cvt ----------------
__global__ void prep_kernel(const float* __restrict__ w0,
                            const float* __restrict__ w1,
                            const float* __restrict__ w2,
                            const float* __restrict__ w3,
                            const float* __restrict__ x,
                            bf16* __restrict__ o0, bf16* __restrict__ o1,
                            bf16* __restrict__ o2, bf16* __restrict__ o3,
                            bf16* __restrict__ xb) {
  if (blockIdx.z == 4) {
    const int blk = blockIdx.y * 32 + blockIdx.x;   // 0..1023
#pragma unroll
    for (int rep = 0; rep < 4; ++rep) {
      const int i = blk * 1024 + rep * 256 + threadIdx.x;  // float4 index
      float4 v = ((const float4*)x)[i];
      ushort4 u;
      u.x = __builtin_bit_cast(unsigned short, __float2bfloat16(v.x));
      u.y = __builtin_bit_cast(unsigned short, __float2bfloat16(v.y));
      u.z = __builtin_bit_cast(unsigned short, __float2bfloat16(v.z));
      u.w = __builtin_bit_cast(unsigned short, __float2bfloat16(v.w));
      ((ushort4*)xb)[i] = u;
    }
    return;
  }
  __shared__ float t[32][33];
  const float* in = blockIdx.z == 0 ? w0 : blockIdx.z == 1 ? w1 : blockIdx.z == 2 ? w2 : w3;
  bf16* out = blockIdx.z == 0 ? o0 : blockIdx.z == 1 ? o1 : blockIdx.z == 2 ? o2 : o3;
  int tx = threadIdx.x & 31;
  int ty = threadIdx.x >> 5;  // 0..7
  int r0 = blockIdx.y * 32;
  int c0 = blockIdx.x * 32;
#pragma unroll
  for (int yy = 0; yy < 32; yy += 8)
    t[ty + yy][tx] = in[(size_t)(r0 + ty + yy) * DM_ + c0 + tx];
  __syncthreads();
#pragma unroll
  for (int yy = 0; yy < 32; yy += 8)
    out[(size_t)(c0 + ty + yy) * DM_ + r0 + tx] = __float2bfloat16(t[tx][ty + yy]);
}

// ---------------- QKV GEMM (2-phase, 128x128, proven; default dispatch) --
// R16 lesson: do NOT XCD-swizzle this grid. Default x-fastest order already
// gives concurrent blocks one shared bn-stripe and per-XCD bm-locality for
// the LARGE operand (A, 8 MB); chunked-bn swizzle made every XCD stream all
// of A through its 4 MB L2 (FETCH 36 MB, 38->58 us).
__global__ __launch_bounds__(256) void gemm_qkv_kernel(
    const bf16* __restrict__ A, const bf16* __restrict__ Bt,
    const float* __restrict__ bias, const float* __restrict__ bias2,
    const float* __restrict__ bias3, bf16* __restrict__ out, int K) {
  __shared__ bf16 As[2][128 * 32];
  __shared__ bf16 Bs[2][128 * 32];
  const int tid = threadIdx.x;
  const int wid = tid >> 6, lane = tid & 63;
  const int g = lane >> 4, c = lane & 15;
  const int wr = wid >> 1, wc = wid & 1;
  const int bm = blockIdx.x, bn = blockIdx.y;

  f32x4 acc[4][4] = {};

  const char* Ag = (const char*)(A + (size_t)bm * 128 * K);
  const char* Bg = (const char*)(Bt + (size_t)bn * 128 * K);
  const int f0 = tid * 16, f1 = f0 + 4096;
  const int r0 = f0 >> 6, cb0 = f0 & 63;
  const int r1 = f1 >> 6;
  const size_t rowbytes = (size_t)K * 2;

  auto stage = [&](int kt, int bufi) {
    const size_t koff = (size_t)kt * 64;
    load16(Ag + (size_t)r0 * rowbytes + koff + cb0, (char*)As[bufi] + f0);
    load16(Ag + (size_t)r1 * rowbytes + koff + cb0, (char*)As[bufi] + f1);
    load16(Bg + (size_t)r0 * rowbytes + koff + cb0, (char*)Bs[bufi] + f0);
    load16(Bg + (size_t)r1 * rowbytes + koff + cb0, (char*)Bs[bufi] + f1);
  };

  const int NT = K / 32;
  stage(0, 0);
  int cur = 0;
#pragma unroll 1
  for (int kt = 0; kt < NT; ++kt) {
    if (kt + 1 < NT) {
      stage(kt + 1, cur ^ 1);
      asm volatile("s_waitcnt vmcnt(4)" ::: "memory");
    } else {
      asm volatile("s_waitcnt vmcnt(0)" ::: "memory");
    }
    __builtin_amdgcn_s_barrier();

    bf16x8 af[4], bfr[4];
#pragma unroll
    for (int mi = 0; mi < 4; ++mi)
      af[mi] = *(const bf16x8*)&As[cur][(wr * 64 + mi * 16 + c) * 32 + g * 8];
#pragma unroll
    for (int ni = 0; ni < 4; ++ni)
      bfr[ni] = *(const bf16x8*)&Bs[cur][(wc * 64 + ni * 16 + c) * 32 + g * 8];
    __builtin_amdgcn_s_setprio(1);
#pragma unroll
    for (int mi = 0; mi < 4; ++mi)
#pragma unroll
      for (int ni = 0; ni < 4; ++ni)
        acc[mi][ni] = MFMA_BF16(af[mi], bfr[ni], acc[mi][ni]);
    __builtin_amdgcn_s_setprio(0);

    if (kt + 1 < NT) __builtin_amdgcn_s_barrier();
    cur ^= 1;
  }

#pragma unroll
  for (int ni = 0; ni < 4; ++ni) {
    const int n_g = bn * 128 + wc * 64 + ni * 16 + c;
    const int proj = n_g >> 10, ncol = n_g & 1023;
    const float bv = proj == 0 ? bias[ncol] : proj == 1 ? bias2[ncol] : bias3[ncol];
    const int h = ncol >> 6, d = ncol & (D_ - 1);
#pragma unroll
    for (int mi = 0; mi < 4; ++mi) {
#pragma unroll
      for (int r = 0; r < 4; ++r) {
        const int m_g = bm * 128 + wr * 64 + mi * 16 + g * 4 + r;
        const float val = acc[mi][ni][r] + bv;
        const int b = m_g >> 11, s = m_g & (S_ - 1);
        size_t idx = (size_t)proj * 4194304;
        if (proj < 2)
          idx += (((size_t)(b * H_ + h)) * S_ + s) * D_ + d;
        else
          idx += (((size_t)(b * H_ + h)) * D_ + d) * S_ + s;
        out[idx] = __float2bfloat16(val);
      }
    }
  }
}

// ---------------- output projection GEMM (2-phase, 128x64 tile) ----------
__global__ __launch_bounds__(256) void gemm_out_kernel(
    const bf16* __restrict__ A, const bf16* __restrict__ Bt,
    const float* __restrict__ bias, float* __restrict__ out, int K) {
  __shared__ bf16 As[2][128 * 32];
  __shared__ bf16 Bs[2][64 * 32];
  const int tid = threadIdx.x;
  const int wid = tid >> 6, lane = tid & 63;
  const int g = lane >> 4, c = lane & 15;
  const int wr = wid >> 1, wc = wid & 1;
  const int bm = blockIdx.x, bn = blockIdx.y;

  f32x4 acc[4][2] = {};

  const char* Ag = (const char*)(A + (size_t)bm * 128 * K);
  const char* Bg = (const char*)(Bt + (size_t)bn * 64 * K);
  const int s0 = tid, s1 = tid + 256;
  const int ra0 = s0 >> 2, ca0 = (s0 & 3) * 16;
  const int ra1 = s1 >> 2, ca1 = (s1 & 3) * 16;
  const int rb = tid >> 2, cb2 = (tid & 3) * 16;
  const size_t rowbytes = (size_t)K * 2;

  auto stage = [&](int kt, int bufi) {
    const size_t koff = (size_t)kt * 64;
    load16(Ag + (size_t)ra0 * rowbytes + koff + ca0, (char*)As[bufi] + s0 * 16);
    load16(Ag + (size_t)ra1 * rowbytes + koff + ca1, (char*)As[bufi] + s1 * 16);
    load16(Bg + (size_t)rb * rowbytes + koff + cb2, (char*)Bs[bufi] + tid * 16);
  };

  const int NT = K / 32;
  stage(0, 0);
  int cur = 0;
#pragma unroll 1
  for (int kt = 0; kt < NT; ++kt) {
    if (kt + 1 < NT) {
      stage(kt + 1, cur ^ 1);
      asm volatile("s_waitcnt vmcnt(3)" ::: "memory");
    } else {
      asm volatile("s_waitcnt vmcnt(0)" ::: "memory");
    }
    __builtin_amdgcn_s_barrier();

    bf16x8 af[4], bfr[2];
#pragma unroll
    for (int mi = 0; mi < 4; ++mi)
      af[mi] = *(const bf16x8*)&As[cur][(wr * 64 + mi * 16 + c) * 32 + g * 8];
#pragma unroll
    for (int ni = 0; ni < 2; ++ni)
      bfr[ni] = *(const bf16x8*)&Bs[cur][(wc * 32 + ni * 16 + c) * 32 + g * 8];
    __builtin_amdgcn_s_setprio(1);
#pragma unroll
    for (int mi = 0; mi < 4; ++mi)
#pragma unroll
      for (int ni = 0; ni < 2; ++ni)
        acc[mi][ni] = MFMA_BF16(af[mi], bfr[ni], acc[mi][ni]);
    __builtin_amdgcn_s_setprio(0);

    if (kt + 1 < NT) __builtin_amdgcn_s_barrier();
    cur ^= 1;
  }

#pragma unroll
  for (int ni = 0; ni < 2; ++ni) {
    const int n_g = bn * 64 + wc * 32 + ni * 16 + c;
    const float bv = bias[n_g];
#pragma unroll
    for (int mi = 0; mi < 4; ++mi) {
#pragma unroll
      for (int r = 0; r < 4; ++r) {
        const int m_g = bm * 128 + wr * 64 + mi * 16 + g * 4 + r;
        out[(size_t)m_g * DM_ + n_g] = acc[mi][ni][r] + bv;
      }
    }
  }
}

// ---------------- flash attention (R13-proven, byte-identical) -----------
// Q,K: (B,H,S,D) bf16 ; Vt: (B,H,D,S) bf16 ; Aout: (B,S,H*D) bf16
// Block = 4 waves = one t-quad of one bh; double-buffered XOR-swizzled LDS
// (__syncthreads pipeline). Swapped-QK^T in-register softmax, defer-max
// gate on per-lane local max (R10), l via ones-MFMA (R12), balanced
// quad->CU mapping (R13). CONFIRMED LOCAL OPTIMUM.
__global__ __launch_bounds__(256, 4) void flash_attn_kernel(
    const bf16* __restrict__ Q, const bf16* __restrict__ Kg,
    const bf16* __restrict__ Vt, bf16* __restrict__ Aout) {
  __shared__ bf16 Ks[2][64 * 64];
  __shared__ bf16 Vs[2][64 * 64];
  const int tid = threadIdx.x;
  const int w = tid >> 6, lane = tid & 63;
  const int g = lane >> 4, c = lane & 15;

  const int bid = blockIdx.x;
  const int xcd = bid & 7, loc = bid >> 3;
  const int bh = xcd * 4 + (loc & 3);
  const int u = loc >> 2;                 // 0..31
  const int slot = u >> 3, q = u & 7;
  const int j = slot == 0 ? 31 - q : slot == 1 ? 16 + q
              : slot == 2 ? 15 - q : q;   // balanced: per-CU sum = 62
  const int t = j * 4 + w;
  const int b = bh >> 4, h = bh & (H_ - 1);

  const float ALPHA2 = 0.125f * 1.44269504f;
  const float THR2 = 11.5f;
  const float NEG_INF = -__builtin_inff();

  const char* Kbase = (const char*)(Kg + (size_t)bh * S_ * D_);
  const char* Vbase = (const char*)(Vt + (size_t)bh * D_ * S_);
  const int s0 = tid, s1 = tid + 256;
  const int sr0 = s0 >> 3, sq0 = ((s0 & 7) ^ (sr0 & 7)) << 4;
  const int sr1 = s1 >> 3, sq1 = ((s1 & 7) ^ (sr1 & 7)) << 4;

  const bf16* Qp = Q + ((size_t)bh * S_ + t * 16 + c) * D_;
  bf16x8 qf[2];
  qf[0] = *(const bf16x8*)&Qp[g * 8];
  qf[1] = *(const bf16x8*)&Qp[32 + g * 8];

  bf16x8 onesf;
#pragma unroll
  for (int jj = 0; jj < 8; ++jj) onesf[jj] = (short)0x3f80;

  f32x4 o[4] = {};
  f32x4 lacc = {};
  float m = -1000.0f;

  const int rowlim = w * 16 + c;
  const int src0 = ((g & 1) * 2) * 16 + c;
  const int src1 = src0 + 16;
  const bool ghi = (g >= 2);
  const int cs = c & 7;
  int roff[2][4];
#pragma unroll
  for (int kk = 0; kk < 2; ++kk)
#pragma unroll
    for (int n = 0; n < 4; ++n)
      roff[kk][n] = n * 2048 + c * 128 + (((kk * 4 + g) ^ cs) << 4);

  {
    load16(Kbase + sr0 * 128 + sq0, (char*)Ks[0] + s0 * 16);
    load16(Kbase + sr1 * 128 + sq1, (char*)Ks[0] + s1 * 16);
    load16(Vbase + sr0 * 4096 + sq0, (char*)Vs[0] + s0 * 16);
    load16(Vbase + sr1 * 4096 + sq1, (char*)Vs[0] + s1 * 16);
  }
  __syncthreads();

  int cur = 0;
#pragma unroll 1
  for (int kv = 0; kv <= j; ++kv) {
    if (kv < j) {
      const char* Krow = Kbase + (size_t)(kv + 1) * 8192;
      const char* Vcol = Vbase + (size_t)(kv + 1) * 128;
      const int nb = cur ^ 1;
      load16(Krow + sr0 * 128 + sq0, (char*)Ks[nb] + s0 * 16);
      load16(Krow + sr1 * 128 + sq1, (char*)Ks[nb] + s1 * 16);
      load16(Vcol + sr0 * 4096 + sq0, (char*)Vs[nb] + s0 * 16);
      load16(Vcol + sr1 * 4096 + sq1, (char*)Vs[nb] + s1 * 16);
    }

    const char* Kt = (const char*)Ks[cur];
    const char* Vtile = (const char*)Vs[cur];
    bf16x8 kf[2][4];
#pragma unroll
    for (int kk = 0; kk < 2; ++kk)
#pragma unroll
      for (int n = 0; n < 4; ++n)
        kf[kk][n] = *(const bf16x8*)(Kt + roff[kk][n]);

    f32x4 st[4] = {};
    __builtin_amdgcn_s_setprio(1);
#pragma unroll
    for (int n = 0; n < 4; ++n) {
      st[n] = MFMA_BF16(kf[0][n], qf[0], st[n]);
      st[n] = MFMA_BF16(kf[1][n], qf[1], st[n]);
    }
    __builtin_amdgcn_s_setprio(0);

    bf16x8 vf[2][4];
#pragma unroll
    for (int kk = 0; kk < 2; ++kk)
#pragma unroll
      for (int n = 0; n < 4; ++n)
        vf[kk][n] = *(const bf16x8*)(Vtile + roff[kk][n]);

    float aa[4][4];
#pragma unroll
    for (int n = 0; n < 4; ++n)
#pragma unroll
      for (int r = 0; r < 4; ++r)
        aa[n][r] = fmaf(st[n][r], ALPHA2, -m);
    if (kv == j) {
#pragma unroll
      for (int n = 0; n < 4; ++n)
#pragma unroll
        for (int r = 0; r < 4; ++r)
          if (n * 16 + g * 4 + r > rowlim) aa[n][r] = NEG_INF;
    }

    float lm;
    {
      float t0 = fmaxf(fmaxf(aa[0][0], aa[0][1]), fmaxf(aa[0][2], aa[0][3]));
      float t1 = fmaxf(fmaxf(aa[1][0], aa[1][1]), fmaxf(aa[1][2], aa[1][3]));
      float t2 = fmaxf(fmaxf(aa[2][0], aa[2][1]), fmaxf(aa[2][2], aa[2][3]));
      float t3 = fmaxf(fmaxf(aa[3][0], aa[3][1]), fmaxf(aa[3][2], aa[3][3]));
      lm = fmaxf(fmaxf(t0, t1), fmaxf(t2, t3));
    }

    if (__any(lm > THR2)) {
      float dm = fmaxf(lm, __shfl_xor(lm, 16, 64));
      dm = fmaxf(dm, __shfl_xor(dm, 32, 64));
      const float sh = fmaxf(dm, 0.0f);
      const float sc = __builtin_amdgcn_exp2f(-sh);
      m += sh;
#pragma unroll
      for (int r = 0; r < 4; ++r) lacc[r] *= sc;
#pragma unroll
      for (int n = 0; n < 4; ++n)
#pragma unroll
        for (int r = 0; r < 4; ++r) o[n][r] *= sc;
#pragma unroll
      for (int n = 0; n < 4; ++n)
#pragma unroll
        for (int r = 0; r < 4; ++r) aa[n][r] -= sh;
    }

    float p[4][4];
#pragma unroll
    for (int n = 0; n < 4; ++n)
#pragma unroll
      for (int r = 0; r < 4; ++r) p[n][r] = __builtin_amdgcn_exp2f(aa[n][r]);

    unsigned int dw[4][2];
#pragma unroll
    for (int n = 0; n < 4; ++n) {
      dw[n][0] = pack_bf16(p[n][0], p[n][1]);
      dw[n][1] = pack_bf16(p[n][2], p[n][3]);
    }

#pragma unroll
    for (int kk = 0; kk < 2; ++kk) {
      unsigned int bb[4];
      {
        unsigned int lo = __shfl(dw[kk * 2][0], src0, 64);
        unsigned int hi = __shfl(dw[kk * 2 + 1][0], src0, 64);
        bb[0] = ghi ? hi : lo;
      }
      {
        unsigned int lo = __shfl(dw[kk * 2][1], src0, 64);
        unsigned int hi = __shfl(dw[kk * 2 + 1][1], src0, 64);
        bb[1] = ghi ? hi : lo;
      }
      {
        unsigned int lo = __shfl(dw[kk * 2][0], src1, 64);
        unsigned int hi = __shfl(dw[kk * 2 + 1][0], src1, 64);
        bb[2] = ghi ? hi : lo;
      }
      {
        unsigned int lo = __shfl(dw[kk * 2][1], src1, 64);
        unsigned int hi = __shfl(dw[kk * 2 + 1][1], src1, 64);
        bb[3] = ghi ? hi : lo;
      }
      u32x4 bbv = {bb[0], bb[1], bb[2], bb[3]};
      bf16x8 pb = __builtin_bit_cast(bf16x8, bbv);
      __builtin_amdgcn_s_setprio(1);
#pragma unroll
      for (int n = 0; n < 4; ++n) o[n] = MFMA_BF16(vf[kk][n], pb, o[n]);
      lacc = MFMA_BF16(onesf, pb, lacc);
      __builtin_amdgcn_s_setprio(0);
    }

    __syncthreads();
    cur ^= 1;
  }

  const float inv = 1.0f / lacc[0];

  bf16* Arow = Aout + ((size_t)b * S_ + t * 16 + c) * (H_ * D_) + h * D_;
#pragma unroll
  for (int n = 0; n < 4; ++n) {
    ushort4 u2;
    u2.x = __builtin_bit_cast(unsigned short, __float2bfloat16(o[n][0] * inv));
    u2.y = __builtin_bit_cast(unsigned short, __float2bfloat16(o[n][1] * inv));
    u2.z = __builtin_bit_cast(unsigned short, __float2bfloat16(o[n][2] * inv));
    u2.w = __builtin_bit_cast(unsigned short, __float2bfloat16(o[n][3] * inv));
    *(ushort4*)&Arow[n * 16 + g * 4] = u2;
  }
}

// ---------------- launcher ----------------

extern "C" void kernel_launch(void* const* d_in, const int* in_sizes, int n_in,
                              void* d_out, int out_size, void* d_ws, size_t ws_size,
                              hipStream_t stream) {
  (void)in_sizes; (void)n_in; (void)out_size; (void)ws_size;
  const float* x  = (const float*)d_in[0];
  const float* Wq = (const float*)d_in[1];
  const float* bq = (const float*)d_in[2];
  const float* Wk = (const float*)d_in[3];
  const float* bk = (const float*)d_in[4];
  const float* Wv = (const float*)d_in[5];
  const float* bv = (const float*)d_in[6];
  const float* Wo = (const float*)d_in[7];
  const float* bo = (const float*)d_in[8];
  float* out = (float*)d_out;

  char* ws = (char*)d_ws;
  bf16* xb  = (bf16*)(ws);                    // 8 MB  (4096x1024 bf16)
  bf16* Wqt = (bf16*)(ws + (8u << 20));       // 2 MB each, CONTIGUOUS (QKV fused)
  bf16* Wkt = (bf16*)(ws + (10u << 20));
  bf16* Wvt = (bf16*)(ws + (12u << 20));
  bf16* Wot = (bf16*)(ws + (14u << 20));
  bf16* Qb  = (bf16*)(ws + (16u << 20));      // 8 MB  (B,H,S,D)  -- +0*4194304
  bf16* Kb  = (bf16*)(ws + (24u << 20));      // 8 MB             -- +1*4194304
  bf16* Vtb = (bf16*)(ws + (32u << 20));      // 8 MB  (B,H,D,S)  -- +2*4194304
  bf16* Ab  = xb;  // attention out reuses xb (xb dead after projections)

  prep_kernel<<<dim3(32, 32, 5), 256, 0, stream>>>(
      Wq, Wk, Wv, Wo, x, Wqt, Wkt, Wvt, Wot, xb);

  // fused QKV projection: Bt = [Wqt;Wkt;Wvt] (3072 rows), 2-phase 128^2
  gemm_qkv_kernel<<<dim3(32, 24), 256, 0, stream>>>(
      xb, Wqt, bq, bk, bv, Qb, DM_);

  flash_attn_kernel<<<dim3(1024), 256, 0, stream>>>(Qb, Kb, Vtb, Ab);

  gemm_out_kernel<<<dim3(32, 16), 256, 0, stream>>>(Ab, Wot, bo, out, DM_);
}